// Round 9
// baseline (159.008 us; speedup 1.0000x reference)
//
#include <hip/hip_runtime.h>
#include <hip/hip_bf16.h>
#include <math.h>

typedef unsigned short u16;
typedef unsigned int u32;
typedef __bf16 bf16x8 __attribute__((ext_vector_type(8)));
typedef short s16x4 __attribute__((ext_vector_type(4)));
typedef float fx4 __attribute__((ext_vector_type(4)));

#define MFMA16(a, b, c) __builtin_amdgcn_mfma_f32_16x16x32_bf16(a, b, c, 0, 0, 0)
// K=16 bf16 MFMA (carried-forward intrinsic; ISA: v_mfma_f32_16x16x16_bf16)
#define MFMAPV(a, b, c) __builtin_amdgcn_mfma_f32_16x16x16bf16_1k(a, b, c, 0, 0, 0)

static constexpr int Bb = 2, Ss = 2048, Dd = 1024, Hh = 16, DKV = 256;
static constexpr int ROWS = Bb * Ss; // 4096
static constexpr float L2T_OVER = 0.0259525632f;  // log2(10000)/512
static constexpr float SC2 = 0.18033688f;         // 0.125 * log2(e)

__device__ __forceinline__ u16 f2bf(float f) {   // RNE
    union { float f; u32 i; } v; v.f = f;
    u32 u = v.i;
    return (u16)((u + 0x7FFFu + ((u >> 16) & 1u)) >> 16);
}
__device__ __forceinline__ u32 f2bfu(float f) {  // RNE, as u32 (P pack)
    u32 u = __float_as_uint(f);
    return (u + 0x7FFFu + ((u >> 16) & 1u)) >> 16;
}

// native transcendentals (r2 win: VALUBusy 66->29%)
__device__ __forceinline__ float fexp2(float x) {
    float r; asm("v_exp_f32 %0, %1" : "=v"(r) : "v"(x)); return r;
}
__device__ __forceinline__ void fsincos(float a, float& sn, float& cs) {
    float r = a * 0.15915494309189535f;  // a >= 0 always here
    r = r - floorf(r);
    asm("v_sin_f32 %0, %1" : "=v"(sn) : "v"(r));
    asm("v_cos_f32 %0, %1" : "=v"(cs) : "v"(r));
}

// async global->LDS, 16B/lane; LDS dest wave-uniform base + lane*16
__device__ __forceinline__ void gl16(const u16* g, u16* l) {
    __builtin_amdgcn_global_load_lds(
        (const __attribute__((address_space(1))) void*)g,
        (__attribute__((address_space(3))) void*)l, 16, 0, 0);
}

template <int CTRL>
__device__ __forceinline__ float dppf(float x) {
    return __int_as_float(
        __builtin_amdgcn_mov_dpp(__float_as_int(x), CTRL, 0xF, 0xF, true));
}

// ---------- merged pre: prep(x->xc bf16, pad bits) + 3 weight transposes ----------
__global__ void pre_kernel(const float* __restrict__ x, const float* __restrict__ Wq,
                           const float* __restrict__ Wk, const float* __restrict__ Wv,
                           u16* __restrict__ xc, u32* __restrict__ kpb,
                           u16* __restrict__ wAll) {
    __shared__ u16 tile[32][33];
    __shared__ int flag;
    int bid = blockIdx.x, t = threadIdx.x;
    if (bid < 4096) {
        int row = bid;
        if (t == 0) flag = 0;
        __syncthreads();
        float4 d = *(const float4*)(x + (size_t)row * Dd + t * 4);
        int any = 0;
        float a0 = d.x, a1 = d.y, a2 = d.z, a3 = d.w;
        if ((__float_as_uint(a0) & 0x7FFFFFFFu) > 0x7F800000u) { a0 = 0.f; any = 1; }
        if ((__float_as_uint(a1) & 0x7FFFFFFFu) > 0x7F800000u) { a1 = 0.f; any = 1; }
        if ((__float_as_uint(a2) & 0x7FFFFFFFu) > 0x7F800000u) { a2 = 0.f; any = 1; }
        if ((__float_as_uint(a3) & 0x7FFFFFFFu) > 0x7F800000u) { a3 = 0.f; any = 1; }
        if (any) atomicOr(&flag, 1);
        uint2 o;
        o.x = (u32)f2bf(a0) | ((u32)f2bf(a1) << 16);
        o.y = (u32)f2bf(a2) | ((u32)f2bf(a3) << 16);
        *(uint2*)(xc + (size_t)row * Dd + t * 4) = o;
        __syncthreads();
        if (t == 0 && flag) {
            int b = row >> 11, s = row & (Ss - 1);
            atomicOr(&kpb[b * 64 + (s >> 5)], 1u << (s & 31));  // idempotent: deterministic
        }
        return;
    }
    // transposes: f32 (R x C) -> bf16 (C x R)
    const float* in; u16* out; int C, bx, by;
    if (bid < 5120) { int i = bid - 4096; in = Wq; out = wAll; C = Dd; bx = i & 31; by = i >> 5; }
    else if (bid < 5376) { int i = bid - 5120; in = Wk; out = wAll + (size_t)Dd * Dd; C = DKV; bx = i & 7; by = i >> 3; }
    else { int i = bid - 5376; in = Wv; out = wAll + (size_t)1280 * Dd; C = DKV; bx = i & 7; by = i >> 3; }
    int c0 = bx * 32, r0 = by * 32;
    int tx = t & 31, ty = t >> 5;
    for (int i = 0; i < 32; i += 8)
        tile[ty + i][tx] = f2bf(in[(size_t)(r0 + ty + i) * C + c0 + tx]);
    __syncthreads();
    for (int i = 0; i < 32; i += 8)
        out[(size_t)(c0 + ty + i) * Dd + r0 + tx] = tile[tx][ty + i];
}

// ------- fused QKV GEMM, BM=128 BN=64 BK=32 (GREEN geometry; BN=128 banned) -------
// q-cols: f32 in-register RoPE (pair partner via dpp lane^1) -> qbuf;
// k-cols: RoPE via repeat-duplication -> kr; v-cols: transposed 8B stores -> vtb.
__global__ __launch_bounds__(256) void gemm_qkv(
    const u16* __restrict__ A, const u16* __restrict__ Bt, u16* __restrict__ qbuf,
    u16* __restrict__ kr, u16* __restrict__ vtb) {
    __shared__ __align__(16) u16 As[2][128 * 32];
    __shared__ __align__(16) u16 Bs[2][64 * 32];
    int t = threadIdx.x, w = t >> 6, lane = t & 63;
    int l15 = lane & 15, quad = lane >> 4;
    int col0 = blockIdx.x * 64, row0 = blockIdx.y * 128;
    int wm = w >> 1, wn = w & 1;  // wave tile 64x32
    fx4 acc[4][2];
#pragma unroll
    for (int i = 0; i < 4; ++i)
#pragma unroll
        for (int j = 0; j < 2; ++j) acc[i][j] = (fx4){0.f, 0.f, 0.f, 0.f};

    auto stage = [&](int kb, int buf) {
#pragma unroll
        for (int i = 0; i < 2; ++i) {
            int slot = i * 256 + t;
            int row = slot >> 2, p = slot & 3, g = p ^ ((row >> 1) & 3);
            gl16(A + (size_t)(row0 + row) * Dd + kb * 32 + g * 8,
                 &As[buf][(i * 256 + w * 64) * 8]);
        }
        {
            int row = t >> 2, p = t & 3, g = p ^ ((row >> 1) & 3);
            gl16(Bt + (size_t)(col0 + row) * Dd + kb * 32 + g * 8,
                 &Bs[buf][(w * 64) * 8]);
        }
    };

    stage(0, 0);
    int buf = 0;
    for (int kb = 0; kb < 32; ++kb) {
        __syncthreads();
        if (kb + 1 < 32) stage(kb + 1, buf ^ 1);
        bf16x8 af[4], bf[2];
#pragma unroll
        for (int mi = 0; mi < 4; ++mi) {
            int row = wm * 64 + mi * 16 + l15;
            af[mi] = *(const bf16x8*)(&As[buf][row * 32 + ((quad ^ ((row >> 1) & 3)) * 8)]);
        }
#pragma unroll
        for (int ni = 0; ni < 2; ++ni) {
            int row = wn * 32 + ni * 16 + l15;
            bf[ni] = *(const bf16x8*)(&Bs[buf][row * 32 + ((quad ^ ((row >> 1) & 3)) * 8)]);
        }
#pragma unroll
        for (int mi = 0; mi < 4; ++mi)
#pragma unroll
            for (int ni = 0; ni < 2; ++ni)
                acc[mi][ni] = MFMA16(af[mi], bf[ni], acc[mi][ni]);
        buf ^= 1;
    }

    if (col0 < 1024) {
        // Q: rope pairs are adjacent cols -> partner value via lane^1 dpp swap
        bool oddc = (l15 & 1) != 0;
#pragma unroll
        for (int mi = 0; mi < 4; ++mi) {
            int rbase = row0 + wm * 64 + mi * 16 + quad * 4;
#pragma unroll
            for (int ni = 0; ni < 2; ++ni) {
                int ccol = col0 + wn * 32 + ni * 16 + l15;
                float f = fexp2(-(float)(ccol >> 1) * L2T_OVER);
#pragma unroll
                for (int r = 0; r < 4; ++r) {
                    float v = acc[mi][ni][r];
                    float p = dppf<0xB1>(v);  // partner lane^1: other half of pair
                    float x0 = oddc ? p : v, x1 = oddc ? v : p;
                    float pos = (float)((rbase + r) & (Ss - 1));
                    float sn, cs;
                    fsincos(pos * f, sn, cs);
                    float res = oddc ? (x0 * sn + x1 * cs) : (x0 * cs - x1 * sn);
                    qbuf[(size_t)(rbase + r) * Dd + ccol] = f2bf(res);
                }
            }
        }
    } else if (col0 < 1280) {
        // K: lane owns k-index tt; repeat duplicates it into both slots of each
        // rope pair -> 4 roped bf16 per row from the single acc value.
#pragma unroll
        for (int mi = 0; mi < 4; ++mi) {
            int rbase = row0 + wm * 64 + mi * 16 + quad * 4;
#pragma unroll
            for (int ni = 0; ni < 2; ++ni) {
                int tt = col0 + wn * 32 + ni * 16 + l15 - 1024;
                float f0 = fexp2(-(float)(2 * tt) * L2T_OVER);
                float f1 = fexp2(-(float)(2 * tt + 1) * L2T_OVER);
#pragma unroll
                for (int r = 0; r < 4; ++r) {
                    int row = rbase + r;
                    float pos = (float)(row & (Ss - 1));
                    float s0, c0, s1, c1;
                    fsincos(pos * f0, s0, c0);
                    fsincos(pos * f1, s1, c1);
                    float kv = acc[mi][ni][r];
                    uint2 o;
                    o.x = (u32)f2bf(kv * (c0 - s0)) | ((u32)f2bf(kv * (s0 + c0)) << 16);
                    o.y = (u32)f2bf(kv * (c1 - s1)) | ((u32)f2bf(kv * (s1 + c1)) << 16);
                    *(uint2*)(kr + (size_t)row * Dd + 4 * tt) = o;
                }
            }
        }
    } else {
        // V: transposed store. Lane's 4 row-values are contiguous in s -> 8B store.
#pragma unroll
        for (int mi = 0; mi < 4; ++mi) {
            int rbase = row0 + wm * 64 + mi * 16 + quad * 4;
            int b = rbase >> 11, s0 = rbase & (Ss - 1);
#pragma unroll
            for (int ni = 0; ni < 2; ++ni) {
                int c = col0 + wn * 32 + ni * 16 + l15 - 1280;
                uint2 o;
                o.x = (u32)f2bf(acc[mi][ni][0]) | ((u32)f2bf(acc[mi][ni][1]) << 16);
                o.y = (u32)f2bf(acc[mi][ni][2]) | ((u32)f2bf(acc[mi][ni][3]) << 16);
                *(uint2*)(vtb + (size_t)(b * DKV + c) * Ss + s0) = o;
            }
        }
    }
}

// -------- flash attention, fixed-M, SPLIT-K slots, SWAPPED-OPERAND PV --------
// Single delta vs green r8: mfma(K,Q) -> S[key=quad*4+r][q=l15]; lane's P values
// are directly the B-fragment of mfma_16x16x16 (n=l15=q, k=quad*4+j=key) and
// V^T rows its A-fragment (m=l15=feat) -> P never touches LDS. Ps deleted
// (LDS 26.6K -> 16.4K; LDS-pipe/iter ~216 -> ~96 cyc). Masks re-derived with
// key<->q roles swapped. Slot combine unchanged (one writer per address).
__global__ __launch_bounds__(256) void attn_kernel(
    const u16* __restrict__ qbuf, const u16* __restrict__ kr,
    const u16* __restrict__ vt, const u32* __restrict__ kpb,
    float* __restrict__ O4, float* __restrict__ L4) {
    __shared__ __align__(16) u16 Ks[2][64 * 64];

    int t = threadIdx.x, w = t >> 6, lane = t & 63;
    int l15 = lane & 15, quad = lane >> 4;
    int bid = blockIdx.x;
    int u = bid >> 5, hh = bid & 31;
    int tile, c;
    if (u < 32)      { tile = 24 + (u & 7); c = u >> 3; }
    else if (u < 56) { tile = 16 + ((u - 32) & 7); c = (u - 32) >> 3; }
    else if (u < 72) { tile = 8 + ((u - 56) & 7); c = (u - 56) >> 3; }
    else             { tile = u - 72; c = 0; }
    int b = hh >> 4, h = hh & 15;
    int n = tile + 1, C = (n + 7) >> 3;               // chunks this tile
    int kb0 = (int)((u32)(n * c) / (u32)C);           // even split
    int kbe = (int)((u32)(n * (c + 1)) / (u32)C);
    int q0 = tile * 64;

    int qq = q0 + w * 16 + l15;  // lane's q row (swapped: q = output col = l15)
    const u16* qp = qbuf + (size_t)(b * Ss + qq) * Dd + h * 64;
    bf16x8 qf0 = *(const bf16x8*)(qp + quad * 8);
    bf16x8 qf1 = *(const bf16x8*)(qp + 32 + quad * 8);

    // pad bitmask preloaded once: lane i holds kpb[b*64+i]; per-iter via __shfl
    u32 pw_all = kpb[b * 64 + lane];

    // V row for this lane: feature l15 of head h, contiguous over keys
    const u16* vrow = vt + (size_t)(b * DKV + h * 16 + l15) * Ss;

    auto stageK = [&](int k0, int buf) {
#pragma unroll
        for (int i2 = 0; i2 < 2; ++i2) {
            int row = i2 * 32 + w * 8 + (lane >> 3);
            int gg = (lane & 7) ^ (row & 7);
            gl16(kr + (size_t)(b * Ss + k0 + row) * Dd + h * 64 + gg * 8,
                 &Ks[buf][(i2 * 32 + w * 8) * 64]);
        }
    };

    float l_lane = 0.f;                       // partial sum for q = qq
    fx4 oacc = (fx4){0.f, 0.f, 0.f, 0.f};

    stageK(kb0 * 64, 0);
    int buf = 0;
    const int qmin = q0 + w * 16;
    const int kk = quad * 4;                  // lane's key sub-offset

    for (int kb = kb0; kb < kbe; ++kb) {
        int k0 = kb * 64;
        __syncthreads();  // drains prefetch vmcnt; prior LDS reads complete
        if (kb + 1 < kbe) stageK(k0 + 64, buf ^ 1);

        // V fragments (PV A-operand): 8B each, issued early, L2-resident
        s16x4 vf[4];
#pragma unroll
        for (int tt = 0; tt < 4; ++tt)
            vf[tt] = *(const s16x4*)(vrow + k0 + tt * 16 + kk);

        // scores SWAPPED: S[key=quad*4+r][q=l15] per 16-key tile tt
        fx4 s[4];
#pragma unroll
        for (int tt = 0; tt < 4; ++tt) {
            const u16* kb_ = &Ks[buf][(tt * 16 + l15) * 64];
            bf16x8 kf0 = *(const bf16x8*)(kb_ + ((quad ^ (l15 & 7)) * 8));
            bf16x8 kf1 = *(const bf16x8*)(kb_ + (((quad + 4) ^ (l15 & 7)) * 8));
            fx4 z = (fx4){0.f, 0.f, 0.f, 0.f};
            fx4 a = MFMA16(kf0, qf0, z);
            s[tt] = MFMA16(kf1, qf1, a);
        }

        u32 pw0 = (u32)__shfl((int)pw_all, 2 * kb, 64);
        u32 pw1 = (u32)__shfl((int)pw_all, 2 * kb + 1, 64);
        bool fast = (k0 + 63 <= qmin) & ((pw0 | pw1) == 0u);

        // fixed-M: e = 2^(s*SC2 - 32); shift-invariant; masked -> 0
        float e[4][4];
        if (fast) {
#pragma unroll
            for (int tt = 0; tt < 4; ++tt)
#pragma unroll
                for (int r = 0; r < 4; ++r)
                    e[tt][r] = fexp2(fmaf(s[tt][r], SC2, -32.f));
        } else {
#pragma unroll
            for (int tt = 0; tt < 4; ++tt) {
                u32 bits = ((tt & 2) ? pw1 : pw0) >> ((tt * 16 + kk) & 31);
                int kbase = k0 + tt * 16 + kk;
#pragma unroll
                for (int r = 0; r < 4; ++r) {
                    float ee = fexp2(fmaf(s[tt][r], SC2, -32.f));
                    e[tt][r] = (kbase + r <= qq && !((bits >> r) & 1u)) ? ee : 0.f;
                }
            }
        }

        // PV: oacc[r] += sum_k P[k][q=l15] * V^T[feat=kk+r][k], K=16 per tt.
        // P packs straight from regs (B-frag n=l15, k=quad*4+j) -- no LDS.
#pragma unroll
        for (int tt = 0; tt < 4; ++tt) {
            l_lane += (e[tt][0] + e[tt][1]) + (e[tt][2] + e[tt][3]);
            union { u32 uu[2]; s16x4 v; } pk;
            pk.uu[0] = f2bfu(e[tt][0]) | (f2bfu(e[tt][1]) << 16);
            pk.uu[1] = f2bfu(e[tt][2]) | (f2bfu(e[tt][3]) << 16);
            oacc = MFMAPV(vf[tt], pk.v, oacc);
        }
        buf ^= 1;
    }

    // epilogue: one writer per address (slot x feature-quad); no atomics.
    float l_red = l_lane;
    l_red += __shfl_xor(l_red, 16, 64);
    l_red += __shfl_xor(l_red, 32, 64);
    size_t slot = ((size_t)hh * Ss + qq) * 4 + c;
    *(fx4*)(&O4[slot * 16 + kk]) = oacc;     // feat kk..kk+3 of query qq
    if (lane < 16) L4[slot] = l_red;         // quad 0, one lane per q
}

// ------- normalize: fixed-order chunk-sum + divide + x4 feature replication -------
__global__ void norm_kernel(const float* __restrict__ O4, const float* __restrict__ L4,
                            float* __restrict__ out) {
    int idx = blockIdx.x * 256 + threadIdx.x;  // float4 index, 1M total
    int d4 = idx & 255;                        // 256 float4 per 1024-wide row
    int row = idx >> 8;                        // b*2048 + s
    int h = d4 >> 4, f = d4 & 15;
    int b = row >> 11, s = row & (Ss - 1);
    int hh = b * 16 + h;
    int Cn = ((s >> 6) + 8) >> 3;              // chunk count for this q's tile
    size_t base = ((size_t)hh * Ss + s) * 4;
    float o = 0.f, l = 0.f;
    for (int c = 0; c < Cn; ++c) {             // fixed order -> deterministic
        o += O4[(base + c) * 16 + f];
        l += L4[base + c];
    }
    float a = o / l;
    float4 o4 = {a, a, a, a};
    *(float4*)(out + (size_t)row * Dd + d4 * 4) = o4;
}

// ---------------- launch ----------------
extern "C" void kernel_launch(void* const* d_in, const int* in_sizes, int n_in,
                              void* d_out, int out_size, void* d_ws, size_t ws_size,
                              hipStream_t stream) {
    const float* x = (const float*)d_in[0];
    const float* Wq = (const float*)d_in[1];
    const float* Wk = (const float*)d_in[2];
    const float* Wv = (const float*)d_in[3];
    float* out = (float*)d_out;

    char* ws = (char*)d_ws;
    const size_t SZ_XC = (size_t)ROWS * Dd * 2;      // 8 MiB  bf16 x
    const size_t SZ_WALL = (size_t)1536 * Dd * 2;    // 3 MiB  W^T (q|k|v)
    const size_t SZ_QB = (size_t)ROWS * Dd * 2;      // 8 MiB  roped Q
    const size_t SZ_KR = (size_t)ROWS * Dd * 2;      // 8 MiB  roped repeated K
    const size_t SZ_VTB = (size_t)Bb * DKV * Ss * 2; // 2 MiB  V^T
    const size_t SZ_KPB = 4096;                      // pad bits
    const size_t SZ_O4 = (size_t)32 * Ss * 4 * 16 * 4; // 16 MiB per-chunk O
    const size_t SZ_L4 = (size_t)32 * Ss * 4 * 4;      // 1 MiB per-chunk l

    size_t off = 0;
    u16* xc = (u16*)(ws + off); off += SZ_XC;
    u16* wAll = (u16*)(ws + off); off += SZ_WALL;
    u16* qbuf = (u16*)(ws + off); off += SZ_QB;
    u16* kr = (u16*)(ws + off); off += SZ_KR;
    u16* vtb = (u16*)(ws + off); off += SZ_VTB;
    u32* kpb = (u32*)(ws + off); off += SZ_KPB;
    float* O4 = (float*)(ws + off); off += SZ_O4;    // no memset: norm reads
    float* L4 = (float*)(ws + off); off += SZ_L4;    // only written slots
    (void)ws_size; (void)in_sizes; (void)n_in; (void)out_size;

    hipMemsetAsync(kpb, 0, SZ_KPB, stream);
    pre_kernel<<<5632, 256, 0, stream>>>(x, Wq, Wk, Wv, xc, kpb, wAll);
    gemm_qkv<<<dim3(1536 / 64, ROWS / 128), 256, 0, stream>>>(xc, wAll, qbuf, kr, vtb);
    attn_kernel<<<2560, 256, 0, stream>>>(qbuf, kr, vtb, kpb, O4, L4);
    norm_kernel<<<4096, 256, 0, stream>>>(O4, L4, out);
}

// Round 10
// 149.270 us; speedup vs baseline: 1.0652x; 1.0652x over previous
//
#include <hip/hip_runtime.h>
#include <hip/hip_bf16.h>
#include <math.h>

typedef unsigned short u16;
typedef unsigned int u32;
typedef __bf16 bf16x8 __attribute__((ext_vector_type(8)));
typedef short s16x4 __attribute__((ext_vector_type(4)));
typedef float fx4 __attribute__((ext_vector_type(4)));

#define MFMA16(a, b, c) __builtin_amdgcn_mfma_f32_16x16x32_bf16(a, b, c, 0, 0, 0)
// K=16 bf16 MFMA (carried-forward intrinsic; ISA: v_mfma_f32_16x16x16_bf16)
#define MFMAPV(a, b, c) __builtin_amdgcn_mfma_f32_16x16x16bf16_1k(a, b, c, 0, 0, 0)

static constexpr int Bb = 2, Ss = 2048, Dd = 1024, Hh = 16, DKV = 256;
static constexpr int ROWS = Bb * Ss; // 4096
static constexpr float L2T_OVER = 0.0259525632f;  // log2(10000)/512
static constexpr float SC2 = 0.18033688f;         // 0.125 * log2(e)

__device__ __forceinline__ u16 f2bf(float f) {   // RNE
    union { float f; u32 i; } v; v.f = f;
    u32 u = v.i;
    return (u16)((u + 0x7FFFu + ((u >> 16) & 1u)) >> 16);
}
__device__ __forceinline__ u32 f2bfu(float f) {  // RNE, as u32 (P pack)
    u32 u = __float_as_uint(f);
    return (u + 0x7FFFu + ((u >> 16) & 1u)) >> 16;
}

// native transcendentals (r2 win: VALUBusy 66->29%)
__device__ __forceinline__ float fexp2(float x) {
    float r; asm("v_exp_f32 %0, %1" : "=v"(r) : "v"(x)); return r;
}
__device__ __forceinline__ void fsincos(float a, float& sn, float& cs) {
    float r = a * 0.15915494309189535f;  // a >= 0 always here
    r = r - floorf(r);
    asm("v_sin_f32 %0, %1" : "=v"(sn) : "v"(r));
    asm("v_cos_f32 %0, %1" : "=v"(cs) : "v"(r));
}

// async global->LDS, 16B/lane; LDS dest wave-uniform base + lane*16
__device__ __forceinline__ void gl16(const u16* g, u16* l) {
    __builtin_amdgcn_global_load_lds(
        (const __attribute__((address_space(1))) void*)g,
        (__attribute__((address_space(3))) void*)l, 16, 0, 0);
}

template <int CTRL>
__device__ __forceinline__ float dppf(float x) {
    return __int_as_float(
        __builtin_amdgcn_mov_dpp(__float_as_int(x), CTRL, 0xF, 0xF, true));
}

// ---------- merged pre: prep(x->xc bf16, pad bits) + 3 weight transposes ----------
__global__ void pre_kernel(const float* __restrict__ x, const float* __restrict__ Wq,
                           const float* __restrict__ Wk, const float* __restrict__ Wv,
                           u16* __restrict__ xc, u32* __restrict__ kpb,
                           u16* __restrict__ wAll) {
    __shared__ u16 tile[32][33];
    __shared__ int flag;
    int bid = blockIdx.x, t = threadIdx.x;
    if (bid < 4096) {
        int row = bid;
        if (t == 0) flag = 0;
        __syncthreads();
        float4 d = *(const float4*)(x + (size_t)row * Dd + t * 4);
        int any = 0;
        float a0 = d.x, a1 = d.y, a2 = d.z, a3 = d.w;
        if ((__float_as_uint(a0) & 0x7FFFFFFFu) > 0x7F800000u) { a0 = 0.f; any = 1; }
        if ((__float_as_uint(a1) & 0x7FFFFFFFu) > 0x7F800000u) { a1 = 0.f; any = 1; }
        if ((__float_as_uint(a2) & 0x7FFFFFFFu) > 0x7F800000u) { a2 = 0.f; any = 1; }
        if ((__float_as_uint(a3) & 0x7FFFFFFFu) > 0x7F800000u) { a3 = 0.f; any = 1; }
        if (any) atomicOr(&flag, 1);
        uint2 o;
        o.x = (u32)f2bf(a0) | ((u32)f2bf(a1) << 16);
        o.y = (u32)f2bf(a2) | ((u32)f2bf(a3) << 16);
        *(uint2*)(xc + (size_t)row * Dd + t * 4) = o;
        __syncthreads();
        if (t == 0 && flag) {
            int b = row >> 11, s = row & (Ss - 1);
            atomicOr(&kpb[b * 64 + (s >> 5)], 1u << (s & 31));  // idempotent: deterministic
        }
        return;
    }
    // transposes: f32 (R x C) -> bf16 (C x R)
    const float* in; u16* out; int C, bx, by;
    if (bid < 5120) { int i = bid - 4096; in = Wq; out = wAll; C = Dd; bx = i & 31; by = i >> 5; }
    else if (bid < 5376) { int i = bid - 5120; in = Wk; out = wAll + (size_t)Dd * Dd; C = DKV; bx = i & 7; by = i >> 3; }
    else { int i = bid - 5376; in = Wv; out = wAll + (size_t)1280 * Dd; C = DKV; bx = i & 7; by = i >> 3; }
    int c0 = bx * 32, r0 = by * 32;
    int tx = t & 31, ty = t >> 5;
    for (int i = 0; i < 32; i += 8)
        tile[ty + i][tx] = f2bf(in[(size_t)(r0 + ty + i) * C + c0 + tx]);
    __syncthreads();
    for (int i = 0; i < 32; i += 8)
        out[(size_t)(c0 + ty + i) * Dd + r0 + tx] = tile[tx][ty + i];
}

// ------- fused QKV GEMM, BM=128 BN=64 BK=32 (GREEN geometry; BN=128 banned) -------
// q-cols: f32 in-register RoPE (pair partner via dpp lane^1) -> qbuf;
// k-cols: RoPE via repeat-duplication -> kr; v-cols: transposed 8B stores -> vtb.
__global__ __launch_bounds__(256) void gemm_qkv(
    const u16* __restrict__ A, const u16* __restrict__ Bt, u16* __restrict__ qbuf,
    u16* __restrict__ kr, u16* __restrict__ vtb) {
    __shared__ __align__(16) u16 As[2][128 * 32];
    __shared__ __align__(16) u16 Bs[2][64 * 32];
    int t = threadIdx.x, w = t >> 6, lane = t & 63;
    int l15 = lane & 15, quad = lane >> 4;
    int col0 = blockIdx.x * 64, row0 = blockIdx.y * 128;
    int wm = w >> 1, wn = w & 1;  // wave tile 64x32
    fx4 acc[4][2];
#pragma unroll
    for (int i = 0; i < 4; ++i)
#pragma unroll
        for (int j = 0; j < 2; ++j) acc[i][j] = (fx4){0.f, 0.f, 0.f, 0.f};

    auto stage = [&](int kb, int buf) {
#pragma unroll
        for (int i = 0; i < 2; ++i) {
            int slot = i * 256 + t;
            int row = slot >> 2, p = slot & 3, g = p ^ ((row >> 1) & 3);
            gl16(A + (size_t)(row0 + row) * Dd + kb * 32 + g * 8,
                 &As[buf][(i * 256 + w * 64) * 8]);
        }
        {
            int row = t >> 2, p = t & 3, g = p ^ ((row >> 1) & 3);
            gl16(Bt + (size_t)(col0 + row) * Dd + kb * 32 + g * 8,
                 &Bs[buf][(w * 64) * 8]);
        }
    };

    stage(0, 0);
    int buf = 0;
    for (int kb = 0; kb < 32; ++kb) {
        __syncthreads();
        if (kb + 1 < 32) stage(kb + 1, buf ^ 1);
        bf16x8 af[4], bf[2];
#pragma unroll
        for (int mi = 0; mi < 4; ++mi) {
            int row = wm * 64 + mi * 16 + l15;
            af[mi] = *(const bf16x8*)(&As[buf][row * 32 + ((quad ^ ((row >> 1) & 3)) * 8)]);
        }
#pragma unroll
        for (int ni = 0; ni < 2; ++ni) {
            int row = wn * 32 + ni * 16 + l15;
            bf[ni] = *(const bf16x8*)(&Bs[buf][row * 32 + ((quad ^ ((row >> 1) & 3)) * 8)]);
        }
#pragma unroll
        for (int mi = 0; mi < 4; ++mi)
#pragma unroll
            for (int ni = 0; ni < 2; ++ni)
                acc[mi][ni] = MFMA16(af[mi], bf[ni], acc[mi][ni]);
        buf ^= 1;
    }

    if (col0 < 1024) {
        // Q: rope pairs are adjacent cols -> partner value via lane^1 dpp swap
        bool oddc = (l15 & 1) != 0;
#pragma unroll
        for (int mi = 0; mi < 4; ++mi) {
            int rbase = row0 + wm * 64 + mi * 16 + quad * 4;
#pragma unroll
            for (int ni = 0; ni < 2; ++ni) {
                int ccol = col0 + wn * 32 + ni * 16 + l15;
                float f = fexp2(-(float)(ccol >> 1) * L2T_OVER);
#pragma unroll
                for (int r = 0; r < 4; ++r) {
                    float v = acc[mi][ni][r];
                    float p = dppf<0xB1>(v);  // partner lane^1: other half of pair
                    float x0 = oddc ? p : v, x1 = oddc ? v : p;
                    float pos = (float)((rbase + r) & (Ss - 1));
                    float sn, cs;
                    fsincos(pos * f, sn, cs);
                    float res = oddc ? (x0 * sn + x1 * cs) : (x0 * cs - x1 * sn);
                    qbuf[(size_t)(rbase + r) * Dd + ccol] = f2bf(res);
                }
            }
        }
    } else if (col0 < 1280) {
        // K: lane owns k-index tt; repeat duplicates it into both slots of each
        // rope pair -> 4 roped bf16 per row from the single acc value.
#pragma unroll
        for (int mi = 0; mi < 4; ++mi) {
            int rbase = row0 + wm * 64 + mi * 16 + quad * 4;
#pragma unroll
            for (int ni = 0; ni < 2; ++ni) {
                int tt = col0 + wn * 32 + ni * 16 + l15 - 1024;
                float f0 = fexp2(-(float)(2 * tt) * L2T_OVER);
                float f1 = fexp2(-(float)(2 * tt + 1) * L2T_OVER);
#pragma unroll
                for (int r = 0; r < 4; ++r) {
                    int row = rbase + r;
                    float pos = (float)(row & (Ss - 1));
                    float s0, c0, s1, c1;
                    fsincos(pos * f0, s0, c0);
                    fsincos(pos * f1, s1, c1);
                    float kv = acc[mi][ni][r];
                    uint2 o;
                    o.x = (u32)f2bf(kv * (c0 - s0)) | ((u32)f2bf(kv * (s0 + c0)) << 16);
                    o.y = (u32)f2bf(kv * (c1 - s1)) | ((u32)f2bf(kv * (s1 + c1)) << 16);
                    *(uint2*)(kr + (size_t)row * Dd + 4 * tt) = o;
                }
            }
        }
    } else {
        // V: transposed store. Lane's 4 row-values are contiguous in s -> 8B store.
#pragma unroll
        for (int mi = 0; mi < 4; ++mi) {
            int rbase = row0 + wm * 64 + mi * 16 + quad * 4;
            int b = rbase >> 11, s0 = rbase & (Ss - 1);
#pragma unroll
            for (int ni = 0; ni < 2; ++ni) {
                int c = col0 + wn * 32 + ni * 16 + l15 - 1280;
                uint2 o;
                o.x = (u32)f2bf(acc[mi][ni][0]) | ((u32)f2bf(acc[mi][ni][1]) << 16);
                o.y = (u32)f2bf(acc[mi][ni][2]) | ((u32)f2bf(acc[mi][ni][3]) << 16);
                *(uint2*)(vtb + (size_t)(b * DKV + c) * Ss + s0) = o;
            }
        }
    }
}

// ------ flash attention, WAVE-DECOUPLED (no loop barriers), swapped PV ------
// r9 finding: attn is latency-bound -- per-iter cost ~1780cyc vs ~400cyc busy,
// invariant across structures; the per-iter __syncthreads+vmcnt(0) couples all
// 4 waves so staging latency never overlaps. Here the 4 waves split the chunk's
// KEY range in quarters; each wave stages its own 32-key K-tiles into a private
// 2x4KB LDS dbuf (gl16 dest is wave-uniform; same-wave consumption => per-wave
// s_waitcnt vmcnt(0) is the only sync). Each wave computes all 64 q rows
// (4 q-subtiles -> 16 MFMA16 + 8 MFMAPV per iter, high ILP). One final barrier
// + fixed-order (w=0..3) in-LDS combine -> same one-writer O4/L4 slots.
// Deterministic: zero cross-wave communication before the final barrier.
__global__ __launch_bounds__(256, 4) void attn_kernel(
    const u16* __restrict__ qbuf, const u16* __restrict__ kr,
    const u16* __restrict__ vt, const u32* __restrict__ kpb,
    float* __restrict__ O4, float* __restrict__ L4) {
    __shared__ __align__(16) u16 KsAll[4][2][32 * 64];   // per-wave dbuf, 32KB

    int t = threadIdx.x, w = t >> 6, lane = t & 63;
    int l15 = lane & 15, quad = lane >> 4;
    int bid = blockIdx.x;
    int u = bid >> 5, hh = bid & 31;
    int tile, c;
    if (u < 32)      { tile = 24 + (u & 7); c = u >> 3; }
    else if (u < 56) { tile = 16 + ((u - 32) & 7); c = (u - 32) >> 3; }
    else if (u < 72) { tile = 8 + ((u - 56) & 7); c = (u - 56) >> 3; }
    else             { tile = u - 72; c = 0; }
    int b = hh >> 4, h = hh & 15;
    int n = tile + 1, C = (n + 7) >> 3;               // chunks this tile
    int kb0 = (int)((u32)(n * c) / (u32)C);           // even split (64-key units)
    int kbe = (int)((u32)(n * (c + 1)) / (u32)C);
    int q0 = tile * 64;

    // this wave's sub-tile range: quarter of the chunk, in 32-key units
    int ST = (kbe - kb0) * 2;
    int ws0 = kb0 * 2 + (ST * w) / 4;
    int ws1 = kb0 * 2 + (ST * (w + 1)) / 4;

    // Q frags for ALL 4 q-subtiles (pre-roped): B-operand, n=l15=q, k=quad*8+j
    bf16x8 qf0[4], qf1[4];
#pragma unroll
    for (int m = 0; m < 4; ++m) {
        const u16* qp = qbuf + (size_t)(b * Ss + q0 + m * 16 + l15) * Dd + h * 64;
        qf0[m] = *(const bf16x8*)(qp + quad * 8);
        qf1[m] = *(const bf16x8*)(qp + 32 + quad * 8);
    }

    u32 pw_all = kpb[b * 64 + lane];  // lane i holds pad word i (32 keys each)
    const u16* vrow = vt + (size_t)(b * DKV + h * 16 + l15) * Ss;
    u16* myK = &KsAll[w][0][0];       // this wave's private [2][2048]

    auto stageK = [&](int sb, int bu) {  // 32 rows x 64 cols, 4 x gl16
#pragma unroll
        for (int i2 = 0; i2 < 4; ++i2) {
            int row = i2 * 8 + (lane >> 3);
            int gg = (lane & 7) ^ (row & 7);
            gl16(kr + (size_t)(b * Ss + sb * 32 + row) * Dd + h * 64 + gg * 8,
                 myK + bu * 2048 + i2 * 512);
        }
    };

    float l_lane[4] = {0.f, 0.f, 0.f, 0.f};
    fx4 oacc[4];
#pragma unroll
    for (int m = 0; m < 4; ++m) oacc[m] = (fx4){0.f, 0.f, 0.f, 0.f};

    if (ws0 < ws1) stageK(ws0, 0);
    int buf = 0;
    const int kk = quad * 4;          // lane's key sub-offset

    for (int sb = ws0; sb < ws1; ++sb) {
        // wave-private sync: drains this wave's K prefetch (issued last iter)
        asm volatile("s_waitcnt vmcnt(0)" ::: "memory");
        __builtin_amdgcn_sched_barrier(0);
        if (sb + 1 < ws1) stageK(sb + 1, buf ^ 1);
        int k0 = sb * 32;
        u32 pw = (u32)__shfl((int)pw_all, sb, 64);

#pragma unroll
        for (int tt = 0; tt < 2; ++tt) {
            const u16* kb_ = myK + buf * 2048 + (tt * 16 + l15) * 64;
            bf16x8 kf0 = *(const bf16x8*)(kb_ + ((quad ^ (l15 & 7)) * 8));
            bf16x8 kf1 = *(const bf16x8*)(kb_ + (((quad + 4) ^ (l15 & 7)) * 8));
            s16x4 vf = *(const s16x4*)(vrow + k0 + tt * 16 + kk);
            int kbase = k0 + tt * 16 + kk;
            u32 bits = pw >> (tt * 16 + kk);
#pragma unroll
            for (int m = 0; m < 4; ++m) {
                fx4 z = (fx4){0.f, 0.f, 0.f, 0.f};
                fx4 a = MFMA16(kf0, qf0[m], z);
                fx4 s = MFMA16(kf1, qf1[m], a);
                float e[4];
                if ((k0 + 31 <= q0 + m * 16) & (pw == 0u)) {
#pragma unroll
                    for (int r = 0; r < 4; ++r)
                        e[r] = fexp2(fmaf(s[r], SC2, -32.f));
                } else {
                    int qq = q0 + m * 16 + l15;
#pragma unroll
                    for (int r = 0; r < 4; ++r) {
                        float ee = fexp2(fmaf(s[r], SC2, -32.f));
                        e[r] = (kbase + r <= qq && !((bits >> r) & 1u)) ? ee : 0.f;
                    }
                }
                l_lane[m] += (e[0] + e[1]) + (e[2] + e[3]);
                union { u32 uu[2]; s16x4 v; } pk;
                pk.uu[0] = f2bfu(e[0]) | (f2bfu(e[1]) << 16);
                pk.uu[1] = f2bfu(e[2]) | (f2bfu(e[3]) << 16);
                oacc[m] = MFMAPV(vf, pk.v, oacc[m]);
            }
        }
        buf ^= 1;
    }

    // per-wave partials -> this wave's own LDS region (K dbuf is dead now;
    // no outstanding gl16: last iteration prefetches nothing)
    float* fw = (float*)myK;          // 2048 floats: [0,1024) O, [1024,1088) l
#pragma unroll
    for (int m = 0; m < 4; ++m) {
        float lr = l_lane[m];
        lr += __shfl_xor(lr, 16, 64);
        lr += __shfl_xor(lr, 32, 64);
        *(fx4*)(fw + (m * 16 + l15) * 16 + kk) = oacc[m];
        if (quad == 0) fw[1024 + m * 16 + l15] = lr;
    }
    __syncthreads();

    // fixed-order combine across waves; one writer per O4/L4 address
    int q = t >> 2, f4 = t & 3;
    fx4 os = (fx4){0.f, 0.f, 0.f, 0.f};
    float ls = 0.f;
#pragma unroll
    for (int wv = 0; wv < 4; ++wv) {
        const float* fv = (const float*)&KsAll[wv][0][0];
        fx4 ov = *(const fx4*)(fv + q * 16 + f4 * 4);
        os[0] += ov[0]; os[1] += ov[1]; os[2] += ov[2]; os[3] += ov[3];
        if (f4 == 0) ls += fv[1024 + q];
    }
    size_t slot = ((size_t)hh * Ss + (q0 + q)) * 4 + c;
    *(fx4*)(&O4[slot * 16 + f4 * 4]) = os;
    if (f4 == 0) L4[slot] = ls;
}

// ------- normalize: fixed-order chunk-sum + divide + x4 feature replication -------
__global__ void norm_kernel(const float* __restrict__ O4, const float* __restrict__ L4,
                            float* __restrict__ out) {
    int idx = blockIdx.x * 256 + threadIdx.x;  // float4 index, 1M total
    int d4 = idx & 255;                        // 256 float4 per 1024-wide row
    int row = idx >> 8;                        // b*2048 + s
    int h = d4 >> 4, f = d4 & 15;
    int b = row >> 11, s = row & (Ss - 1);
    int hh = b * 16 + h;
    int Cn = ((s >> 6) + 8) >> 3;              // chunk count for this q's tile
    size_t base = ((size_t)hh * Ss + s) * 4;
    float o = 0.f, l = 0.f;
    for (int c = 0; c < Cn; ++c) {             // fixed order -> deterministic
        o += O4[(base + c) * 16 + f];
        l += L4[base + c];
    }
    float a = o / l;
    float4 o4 = {a, a, a, a};
    *(float4*)(out + (size_t)row * Dd + d4 * 4) = o4;
}

// ---------------- launch ----------------
extern "C" void kernel_launch(void* const* d_in, const int* in_sizes, int n_in,
                              void* d_out, int out_size, void* d_ws, size_t ws_size,
                              hipStream_t stream) {
    const float* x = (const float*)d_in[0];
    const float* Wq = (const float*)d_in[1];
    const float* Wk = (const float*)d_in[2];
    const float* Wv = (const float*)d_in[3];
    float* out = (float*)d_out;

    char* ws = (char*)d_ws;
    const size_t SZ_XC = (size_t)ROWS * Dd * 2;      // 8 MiB  bf16 x
    const size_t SZ_WALL = (size_t)1536 * Dd * 2;    // 3 MiB  W^T (q|k|v)
    const size_t SZ_QB = (size_t)ROWS * Dd * 2;      // 8 MiB  roped Q
    const size_t SZ_KR = (size_t)ROWS * Dd * 2;      // 8 MiB  roped repeated K
    const size_t SZ_VTB = (size_t)Bb * DKV * Ss * 2; // 2 MiB  V^T
    const size_t SZ_KPB = 4096;                      // pad bits
    const size_t SZ_O4 = (size_t)32 * Ss * 4 * 16 * 4; // 16 MiB per-chunk O
    const size_t SZ_L4 = (size_t)32 * Ss * 4 * 4;      // 1 MiB per-chunk l

    size_t off = 0;
    u16* xc = (u16*)(ws + off); off += SZ_XC;
    u16* wAll = (u16*)(ws + off); off += SZ_WALL;
    u16* qbuf = (u16*)(ws + off); off += SZ_QB;
    u16* kr = (u16*)(ws + off); off += SZ_KR;
    u16* vtb = (u16*)(ws + off); off += SZ_VTB;
    u32* kpb = (u32*)(ws + off); off += SZ_KPB;
    float* O4 = (float*)(ws + off); off += SZ_O4;    // no memset: norm reads
    float* L4 = (float*)(ws + off); off += SZ_L4;    // only written slots
    (void)ws_size; (void)in_sizes; (void)n_in; (void)out_size;

    hipMemsetAsync(kpb, 0, SZ_KPB, stream);
    pre_kernel<<<5632, 256, 0, stream>>>(x, Wq, Wk, Wv, xc, kpb, wAll);
    gemm_qkv<<<dim3(1536 / 64, ROWS / 128), 256, 0, stream>>>(xc, wAll, qbuf, kr, vtb);
    attn_kernel<<<2560, 256, 0, stream>>>(qbuf, kr, vtb, kpb, O4, L4);
    norm_kernel<<<4096, 256, 0, stream>>>(O4, L4, out);
}

// Round 11
// 145.862 us; speedup vs baseline: 1.0901x; 1.0234x over previous
//
#include <hip/hip_runtime.h>
#include <hip/hip_bf16.h>
#include <math.h>

typedef unsigned short u16;
typedef unsigned int u32;
typedef __bf16 bf16x8 __attribute__((ext_vector_type(8)));
typedef float fx4 __attribute__((ext_vector_type(4)));

#define MFMA16(a, b, c) __builtin_amdgcn_mfma_f32_16x16x32_bf16(a, b, c, 0, 0, 0)

static constexpr int Bb = 2, Ss = 2048, Dd = 1024, Hh = 16, DKV = 256;
static constexpr int ROWS = Bb * Ss; // 4096
static constexpr float L2T_OVER = 0.0259525632f;  // log2(10000)/512
static constexpr float SC2 = 0.18033688f;         // 0.125 * log2(e)
static constexpr int PSTR = 76;                   // Ps row stride (bank-spread)

__device__ __forceinline__ u16 f2bf(float f) {   // RNE
    union { float f; u32 i; } v; v.f = f;
    u32 u = v.i;
    return (u16)((u + 0x7FFFu + ((u >> 16) & 1u)) >> 16);
}
__device__ __forceinline__ u16 bfr(float f) {    // RN (cheap), for P tiles
    return (u16)((__float_as_uint(f) + 0x8000u) >> 16);
}

// native transcendentals (r2 win: VALUBusy 66->29%)
__device__ __forceinline__ float fexp2(float x) {
    float r; asm("v_exp_f32 %0, %1" : "=v"(r) : "v"(x)); return r;
}
__device__ __forceinline__ void fsincos(float a, float& sn, float& cs) {
    float r = a * 0.15915494309189535f;  // a >= 0 always here
    r = r - floorf(r);
    asm("v_sin_f32 %0, %1" : "=v"(sn) : "v"(r));
    asm("v_cos_f32 %0, %1" : "=v"(cs) : "v"(r));
}

// async global->LDS, 16B/lane; LDS dest wave-uniform base + lane*16
__device__ __forceinline__ void gl16(const u16* g, u16* l) {
    __builtin_amdgcn_global_load_lds(
        (const __attribute__((address_space(1))) void*)g,
        (__attribute__((address_space(3))) void*)l, 16, 0, 0);
}

template <int CTRL>
__device__ __forceinline__ float dppf(float x) {
    return __int_as_float(
        __builtin_amdgcn_mov_dpp(__float_as_int(x), CTRL, 0xF, 0xF, true));
}
__device__ __forceinline__ float rsum16(float x) {
    x += dppf<0xB1>(x);   // quad_perm [1,0,3,2]
    x += dppf<0x4E>(x);   // quad_perm [2,3,0,1]
    x += dppf<0x124>(x);  // row_ror:4
    x += dppf<0x128>(x);  // row_ror:8
    return x;
}

// ---------- merged pre: prep(x->xc bf16, pad bits) + 3 weight transposes ----------
__global__ void pre_kernel(const float* __restrict__ x, const float* __restrict__ Wq,
                           const float* __restrict__ Wk, const float* __restrict__ Wv,
                           u16* __restrict__ xc, u32* __restrict__ kpb,
                           u16* __restrict__ wAll) {
    __shared__ u16 tile[32][33];
    __shared__ int flag;
    int bid = blockIdx.x, t = threadIdx.x;
    if (bid < 4096) {
        int row = bid;
        if (t == 0) flag = 0;
        __syncthreads();
        float4 d = *(const float4*)(x + (size_t)row * Dd + t * 4);
        int any = 0;
        float a0 = d.x, a1 = d.y, a2 = d.z, a3 = d.w;
        if ((__float_as_uint(a0) & 0x7FFFFFFFu) > 0x7F800000u) { a0 = 0.f; any = 1; }
        if ((__float_as_uint(a1) & 0x7FFFFFFFu) > 0x7F800000u) { a1 = 0.f; any = 1; }
        if ((__float_as_uint(a2) & 0x7FFFFFFFu) > 0x7F800000u) { a2 = 0.f; any = 1; }
        if ((__float_as_uint(a3) & 0x7FFFFFFFu) > 0x7F800000u) { a3 = 0.f; any = 1; }
        if (any) atomicOr(&flag, 1);
        uint2 o;
        o.x = (u32)f2bf(a0) | ((u32)f2bf(a1) << 16);
        o.y = (u32)f2bf(a2) | ((u32)f2bf(a3) << 16);
        *(uint2*)(xc + (size_t)row * Dd + t * 4) = o;
        __syncthreads();
        if (t == 0 && flag) {
            int b = row >> 11, s = row & (Ss - 1);
            atomicOr(&kpb[b * 64 + (s >> 5)], 1u << (s & 31));  // idempotent: deterministic
        }
        return;
    }
    // transposes: f32 (R x C) -> bf16 (C x R)
    const float* in; u16* out; int C, bx, by;
    if (bid < 5120) { int i = bid - 4096; in = Wq; out = wAll; C = Dd; bx = i & 31; by = i >> 5; }
    else if (bid < 5376) { int i = bid - 5120; in = Wk; out = wAll + (size_t)Dd * Dd; C = DKV; bx = i & 7; by = i >> 3; }
    else { int i = bid - 5376; in = Wv; out = wAll + (size_t)1280 * Dd; C = DKV; bx = i & 7; by = i >> 3; }
    int c0 = bx * 32, r0 = by * 32;
    int tx = t & 31, ty = t >> 5;
    for (int i = 0; i < 32; i += 8)
        tile[ty + i][tx] = f2bf(in[(size_t)(r0 + ty + i) * C + c0 + tx]);
    __syncthreads();
    for (int i = 0; i < 32; i += 8)
        out[(size_t)(c0 + ty + i) * Dd + r0 + tx] = tile[tx][ty + i];
}

// ------- fused QKV GEMM, BM=128 BN=64 BK=32 (GREEN geometry; BN=128 banned) -------
// q-cols: f32 in-register RoPE (pair partner via dpp lane^1) -> qbuf;
// k-cols: RoPE via repeat-duplication -> kr; v-cols: transposed 8B stores -> vtb.
__global__ __launch_bounds__(256) void gemm_qkv(
    const u16* __restrict__ A, const u16* __restrict__ Bt, u16* __restrict__ qbuf,
    u16* __restrict__ kr, u16* __restrict__ vtb) {
    __shared__ __align__(16) u16 As[2][128 * 32];
    __shared__ __align__(16) u16 Bs[2][64 * 32];
    int t = threadIdx.x, w = t >> 6, lane = t & 63;
    int l15 = lane & 15, quad = lane >> 4;
    int col0 = blockIdx.x * 64, row0 = blockIdx.y * 128;
    int wm = w >> 1, wn = w & 1;  // wave tile 64x32
    fx4 acc[4][2];
#pragma unroll
    for (int i = 0; i < 4; ++i)
#pragma unroll
        for (int j = 0; j < 2; ++j) acc[i][j] = (fx4){0.f, 0.f, 0.f, 0.f};

    auto stage = [&](int kb, int buf) {
#pragma unroll
        for (int i = 0; i < 2; ++i) {
            int slot = i * 256 + t;
            int row = slot >> 2, p = slot & 3, g = p ^ ((row >> 1) & 3);
            gl16(A + (size_t)(row0 + row) * Dd + kb * 32 + g * 8,
                 &As[buf][(i * 256 + w * 64) * 8]);
        }
        {
            int row = t >> 2, p = t & 3, g = p ^ ((row >> 1) & 3);
            gl16(Bt + (size_t)(col0 + row) * Dd + kb * 32 + g * 8,
                 &Bs[buf][(w * 64) * 8]);
        }
    };

    stage(0, 0);
    int buf = 0;
    for (int kb = 0; kb < 32; ++kb) {
        __syncthreads();
        if (kb + 1 < 32) stage(kb + 1, buf ^ 1);
        bf16x8 af[4], bf[2];
#pragma unroll
        for (int mi = 0; mi < 4; ++mi) {
            int row = wm * 64 + mi * 16 + l15;
            af[mi] = *(const bf16x8*)(&As[buf][row * 32 + ((quad ^ ((row >> 1) & 3)) * 8)]);
        }
#pragma unroll
        for (int ni = 0; ni < 2; ++ni) {
            int row = wn * 32 + ni * 16 + l15;
            bf[ni] = *(const bf16x8*)(&Bs[buf][row * 32 + ((quad ^ ((row >> 1) & 3)) * 8)]);
        }
#pragma unroll
        for (int mi = 0; mi < 4; ++mi)
#pragma unroll
            for (int ni = 0; ni < 2; ++ni)
                acc[mi][ni] = MFMA16(af[mi], bf[ni], acc[mi][ni]);
        buf ^= 1;
    }

    if (col0 < 1024) {
        // Q: rope pairs are adjacent cols -> partner value via lane^1 dpp swap
        bool oddc = (l15 & 1) != 0;
#pragma unroll
        for (int mi = 0; mi < 4; ++mi) {
            int rbase = row0 + wm * 64 + mi * 16 + quad * 4;
#pragma unroll
            for (int ni = 0; ni < 2; ++ni) {
                int ccol = col0 + wn * 32 + ni * 16 + l15;
                float f = fexp2(-(float)(ccol >> 1) * L2T_OVER);
#pragma unroll
                for (int r = 0; r < 4; ++r) {
                    float v = acc[mi][ni][r];
                    float p = dppf<0xB1>(v);  // partner lane^1: other half of pair
                    float x0 = oddc ? p : v, x1 = oddc ? v : p;
                    float pos = (float)((rbase + r) & (Ss - 1));
                    float sn, cs;
                    fsincos(pos * f, sn, cs);
                    float res = oddc ? (x0 * sn + x1 * cs) : (x0 * cs - x1 * sn);
                    qbuf[(size_t)(rbase + r) * Dd + ccol] = f2bf(res);
                }
            }
        }
    } else if (col0 < 1280) {
        // K: lane owns k-index tt; repeat duplicates it into both slots of each
        // rope pair -> 4 roped bf16 per row from the single acc value.
#pragma unroll
        for (int mi = 0; mi < 4; ++mi) {
            int rbase = row0 + wm * 64 + mi * 16 + quad * 4;
#pragma unroll
            for (int ni = 0; ni < 2; ++ni) {
                int tt = col0 + wn * 32 + ni * 16 + l15 - 1024;
                float f0 = fexp2(-(float)(2 * tt) * L2T_OVER);
                float f1 = fexp2(-(float)(2 * tt + 1) * L2T_OVER);
#pragma unroll
                for (int r = 0; r < 4; ++r) {
                    int row = rbase + r;
                    float pos = (float)(row & (Ss - 1));
                    float s0, c0, s1, c1;
                    fsincos(pos * f0, s0, c0);
                    fsincos(pos * f1, s1, c1);
                    float kv = acc[mi][ni][r];
                    uint2 o;
                    o.x = (u32)f2bf(kv * (c0 - s0)) | ((u32)f2bf(kv * (s0 + c0)) << 16);
                    o.y = (u32)f2bf(kv * (c1 - s1)) | ((u32)f2bf(kv * (s1 + c1)) << 16);
                    *(uint2*)(kr + (size_t)row * Dd + 4 * tt) = o;
                }
            }
        }
    } else {
        // V: transposed store. Lane's 4 row-values are contiguous in s -> 8B store.
#pragma unroll
        for (int mi = 0; mi < 4; ++mi) {
            int rbase = row0 + wm * 64 + mi * 16 + quad * 4;
            int b = rbase >> 11, s0 = rbase & (Ss - 1);
#pragma unroll
            for (int ni = 0; ni < 2; ++ni) {
                int c = col0 + wn * 32 + ni * 16 + l15 - 1280;
                uint2 o;
                o.x = (u32)f2bf(acc[mi][ni][0]) | ((u32)f2bf(acc[mi][ni][1]) << 16);
                o.y = (u32)f2bf(acc[mi][ni][2]) | ((u32)f2bf(acc[mi][ni][3]) << 16);
                *(uint2*)(vtb + (size_t)(b * DKV + c) * Ss + s0) = o;
            }
        }
    }
}

// ------- flash attention, Q-TILE=128 (r8-GREEN sync structure), SPLIT-K -------
// r10 finding: the ~42us attn cost tracks the NUMBER of 64-key block-iters
// (66/CU), not the sync style (barrier r8 ~= decoupled r10). So amortize: each
// block covers 128 q rows (wave w owns 2x16-row subtiles) -> K frags read once
// per TWO q-subtiles; staging bytes + barriers per unit work halve (33/CU).
// 16 q-tiles, n=2t+2 iters, <=8-iter chunks -> 40 units x 32 bh = 1280 blocks,
// heavy-first (all chunks 5-8 iters -> naturally balanced). Math per element
// and K-order identical to r8. Slot combine unchanged (one writer/address).
__global__ __launch_bounds__(256) void attn_kernel(
    const u16* __restrict__ qbuf, const u16* __restrict__ kr,
    const u16* __restrict__ vt, const u32* __restrict__ kpb,
    float* __restrict__ O4, float* __restrict__ L4) {
    __shared__ __align__(16) u16 Ks[2][64 * 64];
    __shared__ __align__(16) u16 Ps[4][2][16 * PSTR];  // per-wave, per-subtile

    int t = threadIdx.x, w = t >> 6, lane = t & 63;
    int l15 = lane & 15, quad = lane >> 4;
    int bid = blockIdx.x;
    int u = bid >> 5, hh = bid & 31;
    // heavy-first unit map: u<16: t=12+(u&3),c=u>>2; u<28: t=8+((u-16)&3),c=(u-16)>>2;
    // u<36: t=4+((u-28)&3),c=(u-28)>>2; else t=3-(u-36),c=0
    int tq, c;
    if (u < 16)      { tq = 12 + (u & 3); c = u >> 2; }
    else if (u < 28) { int v = u - 16; tq = 8 + (v & 3); c = v >> 2; }
    else if (u < 36) { int v = u - 28; tq = 4 + (v & 3); c = v >> 2; }
    else             { tq = 3 - (u - 36); c = 0; }
    int b = hh >> 4, h = hh & 15;
    int n = 2 * tq + 2, C = (n + 7) >> 3;             // 64-key iters, chunks
    int kb0 = (int)((u32)(n * c) / (u32)C);           // even split
    int kbe = (int)((u32)(n * (c + 1)) / (u32)C);
    int q0 = tq * 128;

    // Q A-frags for 2 subtiles (pre-roped): m=l15 (q row), k=quad*8+j (dim)
    bf16x8 qf0[2], qf1[2];
#pragma unroll
    for (int m = 0; m < 2; ++m) {
        const u16* qp = qbuf + (size_t)(b * Ss + q0 + w * 32 + m * 16 + l15) * Dd + h * 64;
        qf0[m] = *(const bf16x8*)(qp + quad * 8);
        qf1[m] = *(const bf16x8*)(qp + 32 + quad * 8);
    }

    // pad bitmask preloaded once: lane i holds kpb[b*64+i]; per-iter via __shfl
    u32 pw_all = kpb[b * 64 + lane];

    // V row for this lane: feature l15 of head h, contiguous over keys
    const u16* vrow = vt + (size_t)(b * DKV + h * 16 + l15) * Ss;

    auto stageK = [&](int k0, int buf) {
#pragma unroll
        for (int i2 = 0; i2 < 2; ++i2) {
            int row = i2 * 32 + w * 8 + (lane >> 3);
            int gg = (lane & 7) ^ (row & 7);
            gl16(kr + (size_t)(b * Ss + k0 + row) * Dd + h * 64 + gg * 8,
                 &Ks[buf][(i2 * 32 + w * 8) * 64]);
        }
    };

    float l_lane[2][4] = {{0.f, 0.f, 0.f, 0.f}, {0.f, 0.f, 0.f, 0.f}};
    fx4 oacc[2];
    oacc[0] = (fx4){0.f, 0.f, 0.f, 0.f};
    oacc[1] = (fx4){0.f, 0.f, 0.f, 0.f};

    stageK(kb0 * 64, 0);
    int buf = 0;
    const int qmin = q0 + w * 32;            // lowest q row this wave owns

    for (int kb = kb0; kb < kbe; ++kb) {
        int k0 = kb * 64;
        __syncthreads();  // drains prefetch vmcnt; prior LDS reads complete
        if (kb + 1 < kbe) stageK(k0 + 64, buf ^ 1);

        // V direct global loads, issued early; consumed after QK+softmax
        bf16x8 vf0 = *(const bf16x8*)(vrow + k0 + quad * 8);
        bf16x8 vf1 = *(const bf16x8*)(vrow + k0 + 32 + quad * 8);

        u32 pw0 = (u32)__shfl((int)pw_all, 2 * kb, 64);
        u32 pw1 = (u32)__shfl((int)pw_all, 2 * kb + 1, 64);
        bool fast = (k0 + 63 <= qmin) & ((pw0 | pw1) == 0u);

        // scores for BOTH q-subtiles from ONE set of K fragment reads
        fx4 s[2][4];
#pragma unroll
        for (int tt = 0; tt < 4; ++tt) {
            const u16* kb_ = &Ks[buf][(tt * 16 + l15) * 64];
            bf16x8 kf0 = *(const bf16x8*)(kb_ + ((quad ^ (l15 & 7)) * 8));
            bf16x8 kf1 = *(const bf16x8*)(kb_ + (((quad + 4) ^ (l15 & 7)) * 8));
#pragma unroll
            for (int m = 0; m < 2; ++m) {
                fx4 z = (fx4){0.f, 0.f, 0.f, 0.f};
                fx4 a = MFMA16(qf0[m], kf0, z);
                s[m][tt] = MFMA16(qf1[m], kf1, a);
            }
        }

#pragma unroll
        for (int m = 0; m < 2; ++m) {
            const int qrb = q0 + w * 32 + m * 16 + quad * 4;  // score-row q base
            float e[4][4];
            if (fast) {
#pragma unroll
                for (int tt = 0; tt < 4; ++tt)
#pragma unroll
                    for (int r = 0; r < 4; ++r)
                        e[tt][r] = fexp2(fmaf(s[m][tt][r], SC2, -32.f));
            } else {
                u32 padb[4];
#pragma unroll
                for (int tt = 0; tt < 4; ++tt)
                    padb[tt] = ((tt & 2 ? pw1 : pw0) >> ((tt * 16 + l15) & 31)) & 1u;
#pragma unroll
                for (int r = 0; r < 4; ++r) {
                    int qq = qrb + r;
#pragma unroll
                    for (int tt = 0; tt < 4; ++tt) {
                        float ee = fexp2(fmaf(s[m][tt][r], SC2, -32.f));
                        e[tt][r] = (k0 + tt * 16 + l15 <= qq && !padb[tt]) ? ee : 0.f;
                    }
                }
            }

#pragma unroll
            for (int r = 0; r < 4; ++r) {
                l_lane[m][r] += (e[0][r] + e[1][r]) + (e[2][r] + e[3][r]);
                int prow = (quad * 4 + r) * PSTR + l15;
                Ps[w][m][prow + 0] = bfr(e[0][r]);
                Ps[w][m][prow + 16] = bfr(e[1][r]);
                Ps[w][m][prow + 32] = bfr(e[2][r]);
                Ps[w][m][prow + 48] = bfr(e[3][r]);
            }

            // PV: A=P[m=q l15][k=key], B=V[n=feat l15][k=key]; same-wave LDS
            bf16x8 pf0 = *(const bf16x8*)(&Ps[w][m][l15 * PSTR + quad * 8]);
            bf16x8 pf1 = *(const bf16x8*)(&Ps[w][m][l15 * PSTR + 32 + quad * 8]);
            oacc[m] = MFMA16(pf0, vf0, oacc[m]);
            oacc[m] = MFMA16(pf1, vf1, oacc[m]);
        }
        buf ^= 1;
    }

    // epilogue: private-slot stores (one writer per address, no atomics)
#pragma unroll
    for (int m = 0; m < 2; ++m)
#pragma unroll
        for (int r = 0; r < 4; ++r) {
            float l_row = rsum16(l_lane[m][r]);
            int q = q0 + w * 32 + m * 16 + quad * 4 + r;
            size_t slot = ((size_t)hh * Ss + q) * 4 + c;
            O4[slot * 16 + l15] = oacc[m][r];
            if (l15 == 0) L4[slot] = l_row;
        }
}

// ------- normalize: fixed-order chunk-sum + divide + x4 feature replication -------
__global__ void norm_kernel(const float* __restrict__ O4, const float* __restrict__ L4,
                            float* __restrict__ out) {
    int idx = blockIdx.x * 256 + threadIdx.x;  // float4 index, 1M total
    int d4 = idx & 255;                        // 256 float4 per 1024-wide row
    int row = idx >> 8;                        // b*2048 + s
    int h = d4 >> 4, f = d4 & 15;
    int b = row >> 11, s = row & (Ss - 1);
    int hh = b * 16 + h;
    int Cn = (2 * (s >> 7) + 9) >> 3;          // chunks for this q's 128-tile
    size_t base = ((size_t)hh * Ss + s) * 4;
    float o = 0.f, l = 0.f;
    for (int c = 0; c < Cn; ++c) {             // fixed order -> deterministic
        o += O4[(base + c) * 16 + f];
        l += L4[base + c];
    }
    float a = o / l;
    float4 o4 = {a, a, a, a};
    *(float4*)(out + (size_t)row * Dd + d4 * 4) = o4;
}

// ---------------- launch ----------------
extern "C" void kernel_launch(void* const* d_in, const int* in_sizes, int n_in,
                              void* d_out, int out_size, void* d_ws, size_t ws_size,
                              hipStream_t stream) {
    const float* x = (const float*)d_in[0];
    const float* Wq = (const float*)d_in[1];
    const float* Wk = (const float*)d_in[2];
    const float* Wv = (const float*)d_in[3];
    float* out = (float*)d_out;

    char* ws = (char*)d_ws;
    const size_t SZ_XC = (size_t)ROWS * Dd * 2;      // 8 MiB  bf16 x
    const size_t SZ_WALL = (size_t)1536 * Dd * 2;    // 3 MiB  W^T (q|k|v)
    const size_t SZ_QB = (size_t)ROWS * Dd * 2;      // 8 MiB  roped Q
    const size_t SZ_KR = (size_t)ROWS * Dd * 2;      // 8 MiB  roped repeated K
    const size_t SZ_VTB = (size_t)Bb * DKV * Ss * 2; // 2 MiB  V^T
    const size_t SZ_KPB = 4096;                      // pad bits
    const size_t SZ_O4 = (size_t)32 * Ss * 4 * 16 * 4; // 16 MiB per-chunk O
    const size_t SZ_L4 = (size_t)32 * Ss * 4 * 4;      // 1 MiB per-chunk l

    size_t off = 0;
    u16* xc = (u16*)(ws + off); off += SZ_XC;
    u16* wAll = (u16*)(ws + off); off += SZ_WALL;
    u16* qbuf = (u16*)(ws + off); off += SZ_QB;
    u16* kr = (u16*)(ws + off); off += SZ_KR;
    u16* vtb = (u16*)(ws + off); off += SZ_VTB;
    u32* kpb = (u32*)(ws + off); off += SZ_KPB;
    float* O4 = (float*)(ws + off); off += SZ_O4;    // no memset: norm reads
    float* L4 = (float*)(ws + off); off += SZ_L4;    // only written slots
    (void)ws_size; (void)in_sizes; (void)n_in; (void)out_size;

    hipMemsetAsync(kpb, 0, SZ_KPB, stream);
    pre_kernel<<<5632, 256, 0, stream>>>(x, Wq, Wk, Wv, xc, kpb, wAll);
    gemm_qkv<<<dim3(1536 / 64, ROWS / 128), 256, 0, stream>>>(xc, wAll, qbuf, kr, vtb);
    attn_kernel<<<1280, 256, 0, stream>>>(qbuf, kr, vtb, kpb, O4, L4);
    norm_kernel<<<4096, 256, 0, stream>>>(O4, L4, out);
}